// Round 2
// baseline (146.526 us; speedup 1.0000x reference)
//
#include <hip/hip_runtime.h>
#include <hip/hip_bf16.h>

typedef unsigned short u16;
typedef __attribute__((ext_vector_type(4))) int   int4v;
typedef __attribute__((ext_vector_type(4))) unsigned int uint4v;
typedef __attribute__((ext_vector_type(4))) unsigned short ushort4v;
typedef __attribute__((ext_vector_type(4))) float floatx4;
typedef __attribute__((ext_vector_type(8))) short bf16x8;

#define LRELU_NS 0.01f
#define SK 264   // LDS k-stride (bf16): 256 + 8 pad, 16B-aligned rows

__device__ __forceinline__ float bitsToF(unsigned int b) {
    union { unsigned int u; float f; } v; v.u = b << 16; return v.f;
}
__device__ __forceinline__ float bfLo(unsigned int d) {
    union { unsigned int u; float f; } v; v.u = d << 16; return v.f;
}
__device__ __forceinline__ float bfHi(unsigned int d) {
    union { unsigned int u; float f; } v; v.u = d & 0xffff0000u; return v.f;
}
__device__ __forceinline__ u16 f2bf(float f) {
    __hip_bfloat16 h = __float2bfloat16(f);
    return *reinterpret_cast<u16*>(&h);
}
// 2-op leaky relu: max(x, 0.01x) == (x>=0 ? x : 0.01x) for all finite x
__device__ __forceinline__ float lrelu(float v) {
    return fmaxf(v, LRELU_NS * v);
}
// dtype-adaptive element fetch (isF32 is block-uniform)
__device__ __forceinline__ u16 ldW(const void* p, int i, int isF32) {
    return isF32 ? f2bf(((const float*)p)[i]) : ((const u16*)p)[i];
}
__device__ __forceinline__ float ldF(const void* p, int i, int isF32) {
    return isF32 ? ((const float*)p)[i]
                 : bitsToF((unsigned int)((const u16*)p)[i]);
}

// ---------------------------------------------------------------------------
// Inlined dtype probe (verified). Must be called by all threads of the block.
// ---------------------------------------------------------------------------
__device__ __forceinline__ int computeIsF32(const u16* y, int* cnt, int t) {
    if (t == 0) *cnt = 0;
    __syncthreads();
    if (t < 256) {
        u16 v = y[2 * t];
        int e = (v >> 7) & 0xFF;
        if (v == 0 || (e >= 96 && e < 160)) atomicAdd(cnt, 1);
    }
    __syncthreads();
    return (*cnt < 192) ? 1 : 0;
}

// ---------------------------------------------------------------------------
// Kernel 1: pack — unchanged (verified).
// blocks 0..63: WallT 64x64 transpose tiles; 64..127: W2T; 128..131: biasF.
// ---------------------------------------------------------------------------
__global__ __launch_bounds__(256) void pack_kernel(
    const void* __restrict__ yhat,
    const void* __restrict__ Ws1, const void* __restrict__ Wc1,
    const void* __restrict__ Wb1, const void* __restrict__ Ws2,
    const void* __restrict__ Wc2,
    const void* __restrict__ bs1, const void* __restrict__ bc1,
    const void* __restrict__ bb1, const void* __restrict__ bs2,
    const void* __restrict__ bc2, const void* __restrict__ bb2,
    u16* __restrict__ WallT, u16* __restrict__ W2T, float* __restrict__ biasF)
{
    __shared__ int fcnt;
    const int bid = blockIdx.x, t = threadIdx.x;
    const int isF32 = computeIsF32((const u16*)yhat, &fcnt, t);
    if (bid < 64) {
        __shared__ u16 tile[64][65];
        const int c0 = (bid & 15) * 64;      // col-tile in [0,1024)
        const int k0 = (bid >> 4) * 64;      // k-tile in [0,256)
        const void* src; int coff; int roff = 0;
        if (c0 < 256)      { src = Ws1; coff = c0; }
        else if (c0 < 512) { src = Wc1; coff = c0 - 256; }
        else if (c0 < 768) { src = Wb1; coff = c0 - 512; }
        else               { src = Wb1; coff = c0 - 768; roff = 256; }
        const int cc = t & 63, kk0 = t >> 6;
        #pragma unroll
        for (int i = 0; i < 16; ++i) {
            int kk = kk0 + i * 4;
            tile[kk][cc] = ldW(src, (k0 + kk + roff) * 256 + coff + cc, isF32);
        }
        __syncthreads();
        const int kk2 = t & 63, cc0 = t >> 6;
        #pragma unroll
        for (int i = 0; i < 16; ++i) {
            int cc2 = cc0 + i * 4;
            WallT[(c0 + cc2) * 256 + (k0 + kk2)] = tile[kk2][cc2];
        }
    } else if (bid < 128) {
        int e2 = (bid - 64) * 256 + t;       // < 16384
        int c = e2 >> 8, k = e2 & 255;
        u16 v = 0;
        if (c < 40)                 v = ldW(Ws2, k * 40 + c, isF32);
        else if (c >= 48 && c < 53) v = ldW(Wc2, k * 5 + (c - 48), isF32);
        W2T[c * 256 + k] = v;
    } else {
        int idx = (bid - 128) * 256 + t;     // < 1024
        float v = 0.f;
        if (idx < 256)       v = ldF(bs1, idx, isF32);
        else if (idx < 512)  v = ldF(bc1, idx - 256, isF32);
        else if (idx < 768)  v = ldF(bb1, idx - 512, isF32);
        else if (idx < 808)  v = ldF(bs2, idx - 768, isF32);
        else if (idx < 813)  v = ldF(bc2, idx - 808, isF32);
        else if (idx >= 816 && idx < 821) v = ldF(bb2, idx - 816, isF32);
        biasF[idx] = v;
    }
}

// ---------------------------------------------------------------------------
// Kernel 2: symbols + charges — unchanged (verified).
// ---------------------------------------------------------------------------
__global__ __launch_bounds__(256) void heads_kernel(
    const void* __restrict__ Xv, const u16* __restrict__ WallT,
    const u16* __restrict__ W2T, const float* __restrict__ biasF,
    void* __restrict__ outv)
{
    __shared__ u16 Xs[64 * SK];
    __shared__ u16 Hb[64 * SK];
    __shared__ int fcnt;
    const int t = threadIdx.x;
    const int bm0 = blockIdx.x * 64;
    const int head = blockIdx.y;
    const int isF32 = computeIsF32((const u16*)Xv, &fcnt, t);

    if (isF32) {   // stage X tile [64][256] from fp32, cvt to bf16
        const floatx4* __restrict__ src = (const floatx4*)((const float*)Xv + bm0 * 256);
        #pragma unroll
        for (int it = 0; it < 16; ++it) {
            int cid = t + it * 256;            // 4096 chunks of 4 floats
            int row = cid >> 6, ch = cid & 63;
            floatx4 f = src[cid];
            ushort4v u;
            u[0] = f2bf(f[0]); u[1] = f2bf(f[1]); u[2] = f2bf(f[2]); u[3] = f2bf(f[3]);
            *(ushort4v*)&Xs[row * SK + ch * 4] = u;
        }
    } else {       // stage X tile from bf16
        const int4v* __restrict__ src = (const int4v*)((const u16*)Xv + bm0 * 256);
        #pragma unroll
        for (int it = 0; it < 8; ++it) {
            int cid = t + it * 256;            // 2048 chunks of 8 bf16
            int row = cid >> 5, ch = cid & 31;
            *(int4v*)&Xs[row * SK + ch * 8] = src[cid];
        }
    }
    __syncthreads();

    const int w = t >> 6, l = t & 63;
    const int ml = l & 15, kq = l >> 4, r0 = kq * 4;

    // ---- layer 1: 16 col-tiles; wave does ct = w+4n; 4 M-tiles each ----
    for (int n = 0; n < 4; ++n) {
        const int ct = w + 4 * n;
        floatx4 acc[4] = {};
        #pragma unroll
        for (int ks = 0; ks < 8; ++ks) {
            const int k0 = ks * 32 + kq * 8;
            bf16x8 bf = *(const bf16x8*)&WallT[(head * 256 + ct * 16 + ml) * 256 + k0];
            #pragma unroll
            for (int mt = 0; mt < 4; ++mt) {
                bf16x8 a = *(const bf16x8*)&Xs[(mt * 16 + ml) * SK + k0];
                acc[mt] = __builtin_amdgcn_mfma_f32_16x16x32_bf16(a, bf, acc[mt], 0, 0, 0);
            }
        }
        const int col = ct * 16 + ml;          // [0,256)
        const float bias = biasF[head * 256 + col];   // bs1 | bc1
        #pragma unroll
        for (int mt = 0; mt < 4; ++mt)
            #pragma unroll
            for (int r = 0; r < 4; ++r)
                Hb[(mt * 16 + r0 + r) * SK + col] = f2bf(lrelu(acc[mt][r] + bias));
    }
    __syncthreads();   // Hb complete

    // ---- layer 2: wave w owns M-tile mt = w ----
    const int nct = (head == 0) ? 3 : 1;       // block-uniform
    const int c0  = (head == 0) ? 0 : 48;
    floatx4 acc2[3] = {};
    #pragma unroll
    for (int ks = 0; ks < 8; ++ks) {
        const int k0 = ks * 32 + kq * 8;
        bf16x8 a = *(const bf16x8*)&Hb[(w * 16 + ml) * SK + k0];
        #pragma unroll
        for (int j = 0; j < 3; ++j) {
            if (j < nct) {
                bf16x8 bf = *(const bf16x8*)&W2T[(c0 + j * 16 + ml) * 256 + k0];
                acc2[j] = __builtin_amdgcn_mfma_f32_16x16x32_bf16(a, bf, acc2[j], 0, 0, 0);
            }
        }
    }
    #pragma unroll
    for (int j = 0; j < 3; ++j) {
        if (j < nct) {
            const int col = j * 16 + ml;
            const int lim = (head == 0) ? 40 : 5;
            if (col < lim) {
                const float bias = biasF[(head == 0 ? 768 : 808) + col];
                #pragma unroll
                for (int r = 0; r < 4; ++r) {
                    const int row = bm0 + w * 16 + r0 + r;
                    const int o = (head == 0) ? row * 40 + col
                                              : 409600 + row * 5 + col;
                    const float v = acc2[j][r] + bias;
                    if (isF32) ((float*)outv)[o] = v;
                    else ((__hip_bfloat16*)outv)[o] = __float2bfloat16(v);
                }
            }
        }
    }
}

// ---------------------------------------------------------------------------
// Kernel 3a: bonds L1 — P = X @ Wb1 (+bb1 on P1 half) computed ONCE,
// written to workspace as bf16. grid (160,4) x 512; block = 64-atom tile,
// y selects 8 of 32 col-tiles. MFMA tiling identical to the verified
// bonds L1 (same A/B frags, same accumulation order) -> identical P bits.
// ---------------------------------------------------------------------------
__global__ __launch_bounds__(512) void l1p_kernel(
    const void* __restrict__ Xv, const u16* __restrict__ WallT,
    const float* __restrict__ biasF,
    u16* __restrict__ P1g, u16* __restrict__ P2g)
{
    __shared__ u16 Xs[64 * SK];
    __shared__ int fcnt;
    const int t = threadIdx.x;
    const int bm0 = blockIdx.x * 64;
    const int isF32 = computeIsF32((const u16*)Xv, &fcnt, t);

    if (isF32) {
        const floatx4* __restrict__ src = (const floatx4*)((const float*)Xv + bm0 * 256);
        #pragma unroll
        for (int s = 0; s < 8; ++s) {
            int cid = t + s * 512;             // < 4096 chunks of 4 floats
            int row = cid >> 6, ch = cid & 63;
            floatx4 f = src[cid];
            ushort4v u;
            u[0] = f2bf(f[0]); u[1] = f2bf(f[1]); u[2] = f2bf(f[2]); u[3] = f2bf(f[3]);
            *(ushort4v*)&Xs[row * SK + ch * 4] = u;
        }
    } else {
        const int4v* __restrict__ src = (const int4v*)((const u16*)Xv + bm0 * 256);
        #pragma unroll
        for (int s = 0; s < 4; ++s) {
            int cid = t + s * 512;             // < 2048 chunks of 8 bf16
            int row = cid >> 5, ch = cid & 31;
            *(int4v*)&Xs[row * SK + ch * 8] = src[cid];
        }
    }
    __syncthreads();

    const int w = t >> 6, l = t & 63;
    const int ml = l & 15, kq = l >> 4, r0 = kq * 4;
    const int ct = blockIdx.y * 8 + w;         // [0,32)
    const int gc = ct * 16 + ml;               // [0,512)

    floatx4 acc[4] = {};
    #pragma unroll
    for (int ks = 0; ks < 8; ++ks) {
        const int k0 = ks * 32 + kq * 8;
        bf16x8 bf = *(const bf16x8*)&WallT[(512 + gc) * 256 + k0];
        #pragma unroll
        for (int mt = 0; mt < 4; ++mt) {
            bf16x8 a = *(const bf16x8*)&Xs[(mt * 16 + ml) * SK + k0];
            acc[mt] = __builtin_amdgcn_mfma_f32_16x16x32_bf16(a, bf, acc[mt], 0, 0, 0);
        }
    }
    const float bias = (gc < 256) ? biasF[512 + gc] : 0.f;   // bb1 on P1 only
    u16* __restrict__ dst = (gc < 256) ? P1g : P2g;
    const int col = gc & 255;
    #pragma unroll
    for (int mt = 0; mt < 4; ++mt)
        #pragma unroll
        for (int r = 0; r < 4; ++r)
            dst[(bm0 + mt * 16 + r0 + r) * 256 + col] = f2bf(acc[mt][r] + bias);
}

// ---------------------------------------------------------------------------
// Kernel 3b: fused symmetric pair phase.
// bonds_sym[i,j] = sum_k ( lrelu(P1[i]+P2[j]) + lrelu(P1[j]+P2[i]) ) * Wb2[k]
//                  + 2*bb2
// One bf16 convert + one MFMA per unordered pair (was 2 each + fbuf pass).
// grid (256 mols, 6 triangle tile-pairs) x 512. LDS 42.2 KB -> 3 blocks/CU.
// Writes final output directly (value + mirror); no symmetrize pass.
// ---------------------------------------------------------------------------
__global__ __launch_bounds__(512, 4) void pairf_kernel(
    const void* __restrict__ Xv,               // yhat, dtype probe only
    const u16* __restrict__ P1g, const u16* __restrict__ P2g,
    const void* __restrict__ Wb2, const float* __restrict__ biasF,
    void* __restrict__ outv)
{
    __shared__ u16 Pq[4][16 * SK];   // [0]=P1 it-tile, [1]=P2 it, [2]=P1 jt, [3]=P2 jt
    __shared__ u16 WsB[16 * 264];
    __shared__ int fcnt;
    const int t = threadIdx.x, mol = blockIdx.x;
    const int y = blockIdx.y;                  // 0..5 -> triangle (it<=jt)
    const int it = (y < 3) ? 0 : (y < 5) ? 1 : 2;
    const int jt = (y < 3) ? y : (y < 5) ? (y - 2) : 2;
    const int isF32 = computeIsF32((const u16*)Xv, &fcnt, t);

    // stage the two P tile-pairs (bf16 from workspace; rows >=40 zeroed)
    #pragma unroll
    for (int s = 0; s < 4; ++s) {
        const int cid = t + s * 512;           // < 2048
        const int buf = cid >> 9, r = (cid >> 5) & 15, ch = cid & 31;
        const int tile = (buf < 2) ? it : jt;
        const u16* __restrict__ src = (buf & 1) ? P2g : P1g;
        const int arow = tile * 16 + r;
        int4v v = {0, 0, 0, 0};
        if (arow < 40) v = *(const int4v*)&src[(mol * 40 + arow) * 256 + ch * 8];
        *(int4v*)&Pq[buf][r * SK + ch * 8] = v;
    }
    // stage Wb2 -> WsB[16][264] (rows 5..15 zero)
    #pragma unroll
    for (int s = 0; s < 8; ++s) {
        const int e2 = t + s * 512;            // < 4096
        const int c = e2 >> 8, k = e2 & 255;
        WsB[c * 264 + k] = (c < 5) ? ldW(Wb2, k * 5 + c, isF32) : (u16)0;
    }
    __syncthreads();

    const int w = t >> 6, l = t & 63;
    const int ml = l & 15, kq = l >> 4, r0 = kq * 4;

    bf16x8 wf[8];
    #pragma unroll
    for (int ks = 0; ks < 8; ++ks)
        wf[ks] = *(const bf16x8*)&WsB[ml * 264 + ks * 32 + kq * 8];
    const float b2x2 = 2.f * biasF[816 + ml];  // bb2*2 (ml<5 used; >=5 reads zeros)

    for (int ii = 0; ii < 2; ++ii) {
        const int iloc = w + 8 * ii;
        const int i = it * 16 + iloc;
        if (i >= 40) continue;                 // wave-uniform
        floatx4 acc = {};
        #pragma unroll
        for (int ks = 0; ks < 8; ++ks) {
            const int k0 = ks * 32 + kq * 8;
            uint4v a1 = *(const uint4v*)&Pq[0][iloc * SK + k0];   // P1[i] (broadcast)
            uint4v a2 = *(const uint4v*)&Pq[1][iloc * SK + k0];   // P2[i] (broadcast)
            uint4v b1 = *(const uint4v*)&Pq[2][ml * SK + k0];     // P1[j]
            uint4v b2 = *(const uint4v*)&Pq[3][ml * SK + k0];     // P2[j]
            bf16x8 af;
            #pragma unroll
            for (int d = 0; d < 4; ++d) {
                const float sLo = lrelu(bfLo(a1[d]) + bfLo(b2[d]))
                                + lrelu(bfLo(b1[d]) + bfLo(a2[d]));
                const float sHi = lrelu(bfHi(a1[d]) + bfHi(b2[d]))
                                + lrelu(bfHi(b1[d]) + bfHi(a2[d]));
                af[2 * d]     = (short)f2bf(sLo);
                af[2 * d + 1] = (short)f2bf(sHi);
            }
            acc = __builtin_amdgcn_mfma_f32_16x16x32_bf16(af, wf[ks], acc, 0, 0, 0);
        }
        if (ml < 5) {                          // D: row=kq*4+r -> j', col=ml -> class
            #pragma unroll
            for (int r = 0; r < 4; ++r) {
                const int j = jt * 16 + r0 + r;
                if (j < 40 && (it != jt || j >= i)) {
                    const float v = acc[r] + b2x2;
                    const int o1 = 460800 + (mol * 1600 + i * 40 + j) * 5 + ml;
                    if (isF32) ((float*)outv)[o1] = v;
                    else ((__hip_bfloat16*)outv)[o1] = __float2bfloat16(v);
                    if (it != jt || j > i) {
                        const int o2 = 460800 + (mol * 1600 + j * 40 + i) * 5 + ml;
                        if (isF32) ((float*)outv)[o2] = v;
                        else ((__hip_bfloat16*)outv)[o2] = __float2bfloat16(v);
                    }
                }
            }
        }
    }
}

// ---------------------------------------------------------------------------
// Kernel 3 (FALLBACK, verified): monolithic bonds — used only if ws_size is
// too small for the P1/P2 workspace of the new pipeline.
// ---------------------------------------------------------------------------
__global__ __launch_bounds__(512) void bonds_kernel(
    const void* __restrict__ Xv, const u16* __restrict__ WallT,
    const void* __restrict__ Wb2, const float* __restrict__ biasF,
    void* __restrict__ outv)
{
    __shared__ u16 Xm[48 * SK];
    __shared__ u16 P1L[48 * SK];
    __shared__ u16 P2L[48 * SK];
    __shared__ u16 WsB[16 * 264];
    __shared__ float fbuf[8000];
    __shared__ int fcnt;
    const int t = threadIdx.x, b = blockIdx.x;
    const int isF32 = computeIsF32((const u16*)Xv, &fcnt, t);

    if (isF32) {
        const floatx4* __restrict__ src = (const floatx4*)((const float*)Xv + b * 10240);
        #pragma unroll
        for (int it = 0; it < 5; ++it) {
            int cid = t + it * 512;
            int row = cid >> 6, ch = cid & 63;
            floatx4 f = src[cid];
            ushort4v u;
            u[0] = f2bf(f[0]); u[1] = f2bf(f[1]); u[2] = f2bf(f[2]); u[3] = f2bf(f[3]);
            *(ushort4v*)&Xm[row * SK + ch * 4] = u;
        }
        {
            int row = 40 + (t >> 6), ch = t & 63;
            ushort4v z = {0, 0, 0, 0};
            *(ushort4v*)&Xm[row * SK + ch * 4] = z;
        }
    } else {
        const int4v* __restrict__ src = (const int4v*)((const u16*)Xv + b * 10240);
        #pragma unroll
        for (int it = 0; it < 3; ++it) {
            int cid = t + it * 512;
            int row = cid >> 5, ch = cid & 31;
            if (cid < 1280) *(int4v*)&Xm[row * SK + ch * 8] = src[cid];
            else { int4v z = {0, 0, 0, 0}; *(int4v*)&Xm[row * SK + ch * 8] = z; }
        }
    }
    #pragma unroll
    for (int it = 0; it < 8; ++it) {
        int e2 = t + it * 512;
        int c = e2 >> 8, k = e2 & 255;
        WsB[c * 264 + k] = (c < 5) ? ldW(Wb2, k * 5 + c, isF32) : (u16)0;
    }
    __syncthreads();

    const int w = t >> 6, l = t & 63;
    const int ml = l & 15, kq = l >> 4, r0 = kq * 4;

    for (int n = 0; n < 4; ++n) {
        const int gc = (w + 8 * n) * 16 + ml;
        floatx4 acc[3] = {};
        #pragma unroll
        for (int ks = 0; ks < 8; ++ks) {
            const int k0 = ks * 32 + kq * 8;
            bf16x8 bf = *(const bf16x8*)&WallT[(512 + gc) * 256 + k0];
            #pragma unroll
            for (int i = 0; i < 3; ++i) {
                bf16x8 a = *(const bf16x8*)&Xm[(i * 16 + ml) * SK + k0];
                acc[i] = __builtin_amdgcn_mfma_f32_16x16x32_bf16(a, bf, acc[i], 0, 0, 0);
            }
        }
        u16* dst = (gc < 256) ? P1L : P2L;
        const int col = gc & 255;
        const float bias = (gc < 256) ? biasF[512 + gc] : 0.f;
        #pragma unroll
        for (int i = 0; i < 3; ++i)
            #pragma unroll
            for (int r = 0; r < 4; ++r)
                dst[(i * 16 + r0 + r) * SK + col] = f2bf(acc[i][r] + bias);
    }
    __syncthreads();

    bf16x8 wf[8];
    #pragma unroll
    for (int ks = 0; ks < 8; ++ks)
        wf[ks] = *(const bf16x8*)&WsB[ml * 264 + ks * 32 + kq * 8];

    for (int m = 0; m < 5; ++m) {
        const int i = w + 8 * m;
        uint4v pa8[8];
        #pragma unroll
        for (int ks = 0; ks < 8; ++ks)
            pa8[ks] = *(const uint4v*)&P1L[i * SK + ks * 32 + kq * 8];
        for (int jt = 0; jt < 3; ++jt) {
            floatx4 acc = {};
            #pragma unroll
            for (int ks = 0; ks < 8; ++ks) {
                const int k0 = ks * 32 + kq * 8;
                uint4v pa = pa8[ks];
                uint4v pb = *(const uint4v*)&P2L[(jt * 16 + ml) * SK + k0];
                bf16x8 af;
                #pragma unroll
                for (int d = 0; d < 4; ++d) {
                    af[2 * d]     = (short)f2bf(lrelu(bfLo(pa[d]) + bfLo(pb[d])));
                    af[2 * d + 1] = (short)f2bf(lrelu(bfHi(pa[d]) + bfHi(pb[d])));
                }
                acc = __builtin_amdgcn_mfma_f32_16x16x32_bf16(af, wf[ks], acc, 0, 0, 0);
            }
            if (ml < 5) {
                #pragma unroll
                for (int r = 0; r < 4; ++r) {
                    const int j = jt * 16 + r0 + r;
                    if (j < 40) fbuf[(i * 40 + j) * 5 + ml] = acc[r];
                }
            }
        }
    }
    __syncthreads();

    const int base = 460800 + b * 8000;
    for (int e = t; e < 8000; e += 512) {
        int pr = e / 5, c = e - pr * 5;
        int i = pr / 40, j = pr - (pr / 40) * 40;
        float v = fbuf[e] + fbuf[(j * 40 + i) * 5 + c] + 2.f * biasF[816 + c];
        if (isF32) ((float*)outv)[base + e] = v;
        else ((__hip_bfloat16*)outv)[base + e] = __float2bfloat16(v);
    }
}

// ---------------------------------------------------------------------------
extern "C" void kernel_launch(void* const* d_in, const int* in_sizes, int n_in,
                              void* d_out, int out_size, void* d_ws, size_t ws_size,
                              hipStream_t stream)
{
    const void* yhat = d_in[0];
    const void* Ws1  = d_in[1];
    const void* bs1  = d_in[2];
    const void* Ws2  = d_in[3];
    const void* bs2  = d_in[4];
    const void* Wc1  = d_in[5];
    const void* bc1  = d_in[6];
    const void* Wc2  = d_in[7];
    const void* bc2  = d_in[8];
    const void* Wb1  = d_in[9];
    const void* bb1  = d_in[10];
    const void* Wb2  = d_in[11];
    const void* bb2  = d_in[12];

    // workspace layout:
    //   [4096, 8192)        biasF  (1024 f32)
    //   [8192, 40960)       W2T    (64*256 bf16)
    //   [40960, 565248)     WallT  (1024*256 bf16)
    //   [565248, +5242880)  P1g    (10240*256 bf16)   } new bonds pipeline
    //   [.., +5242880)      P2g    (10240*256 bf16)   }
    char* wsb = (char*)d_ws;
    float* biasF = (float*)(wsb + 4096);
    u16*   W2T   = (u16*)(wsb + 8192);
    u16*   WallT = (u16*)(wsb + 40960);
    const size_t P_OFF   = 565248;
    const size_t P_BYTES = (size_t)10240 * 256 * 2;   // 5242880
    const bool big = ws_size >= P_OFF + 2 * P_BYTES;  // 11,051,008 B

    pack_kernel<<<132, 256, 0, stream>>>(yhat, Ws1, Wc1, Wb1, Ws2, Wc2,
                                         bs1, bc1, bb1, bs2, bc2, bb2,
                                         WallT, W2T, biasF);
    heads_kernel<<<dim3(160, 2), 256, 0, stream>>>(yhat, WallT, W2T, biasF, d_out);
    if (big) {
        u16* P1g = (u16*)(wsb + P_OFF);
        u16* P2g = (u16*)(wsb + P_OFF + P_BYTES);
        l1p_kernel<<<dim3(160, 4), 512, 0, stream>>>(yhat, WallT, biasF, P1g, P2g);
        pairf_kernel<<<dim3(256, 6), 512, 0, stream>>>(yhat, P1g, P2g, Wb2, biasF, d_out);
    } else {
        bonds_kernel<<<256, 512, 0, stream>>>(yhat, WallT, Wb2, biasF, d_out);
    }
}